// Round 1
// 1251.203 us; speedup vs baseline: 1.0579x; 1.0579x over previous
//
#include <hip/hip_runtime.h>

#define DIM 1024
#define HEADS 16
#define HEAD_DIM 64
#define NTOK 49
#define SCALEF 0.125f

typedef __attribute__((ext_vector_type(8))) short bf16x8;
typedef __attribute__((ext_vector_type(4))) float floatx4;
typedef __attribute__((ext_vector_type(16))) float floatx16;
typedef __attribute__((ext_vector_type(4))) unsigned int uintx4;

typedef const __attribute__((address_space(1))) void* gptr_t;
typedef __attribute__((address_space(3))) void* sptr_t;

__device__ __forceinline__ void async_load16(const void* g, void* s) {
    __builtin_amdgcn_global_load_lds((gptr_t)g, (sptr_t)s, 16, 0, 0);
}

__device__ __forceinline__ unsigned short f2bf(float f) {
    unsigned int u = __builtin_bit_cast(unsigned int, f);
    u = (u + 0x7fffu + ((u >> 16) & 1u)) >> 16;
    return (unsigned short)u;
}

// ---------------- fp32 -> bf16 convert, two arrays fused -------------------
__global__ void cvt2_kernel(const float* __restrict__ a, const float* __restrict__ b,
                            unsigned short* __restrict__ oa, unsigned short* __restrict__ ob,
                            int n) {
    int i = (blockIdx.x * 256 + threadIdx.x) * 4;
    if (i >= n) return;
    float4 va = *(const float4*)&a[i];
    float4 vb = *(const float4*)&b[i];
    ushort4 ua = make_ushort4(f2bf(va.x), f2bf(va.y), f2bf(va.z), f2bf(va.w));
    ushort4 ub = make_ushort4(f2bf(vb.x), f2bf(vb.y), f2bf(vb.z), f2bf(vb.w));
    *(ushort4*)&oa[i] = ua;
    *(ushort4*)&ob[i] = ub;
}

// ---------------- GEMM: C[m,n] = sum_k A[m,k]*B[n,k] + bias[n] -------------
template <bool OUT_BF16>
__global__ __launch_bounds__(256)
void gemm_bt_kernel(const unsigned short* __restrict__ A,
                    const unsigned short* __restrict__ Bw,
                    const float* __restrict__ bias,
                    void* __restrict__ Cout) {
    constexpr int K = 1024, N = 1024;
    __shared__ unsigned short As[128 * 32];
    __shared__ unsigned short Bs[128 * 32];
    const int tid = threadIdx.x;
    const int lane = tid & 63;
    const int wave = tid >> 6;
    const int wm = (wave >> 1) * 64;
    const int wn = (wave & 1) * 64;
    const int m0 = blockIdx.y * 128;
    const int n0 = blockIdx.x * 128;
    const int lr = lane & 15;
    const int lk = (lane >> 4) * 8;

    floatx4 acc[4][4] = {};

    for (int kt = 0; kt < K / 32; ++kt) {
        const int kbase = kt * 32;
#pragma unroll
        for (int j = 0; j < 2; ++j) {
            int off = tid * 16 + j * 4096;
            int r = off >> 6;
            int ce = (off & 63) >> 1;
            async_load16(A + (size_t)(m0 + r) * K + kbase + ce, (char*)As + off);
            async_load16(Bw + (size_t)(n0 + r) * K + kbase + ce, (char*)Bs + off);
        }
        __syncthreads();
        bf16x8 af[4], bfr[4];
#pragma unroll
        for (int t = 0; t < 4; ++t) {
            af[t]  = *(const bf16x8*)&As[(wm + t * 16 + lr) * 32 + lk];
            bfr[t] = *(const bf16x8*)&Bs[(wn + t * 16 + lr) * 32 + lk];
        }
#pragma unroll
        for (int mt = 0; mt < 4; ++mt)
#pragma unroll
            for (int nt = 0; nt < 4; ++nt)
                acc[mt][nt] = __builtin_amdgcn_mfma_f32_16x16x32_bf16(
                    af[mt], bfr[nt], acc[mt][nt], 0, 0, 0);
        __syncthreads();
    }

#pragma unroll
    for (int mt = 0; mt < 4; ++mt) {
#pragma unroll
        for (int nt = 0; nt < 4; ++nt) {
            int col = n0 + wn + nt * 16 + (lane & 15);
            float bv = bias[col];
#pragma unroll
            for (int r = 0; r < 4; ++r) {
                int row = m0 + wm + mt * 16 + (lane >> 4) * 4 + r;
                float v = acc[mt][nt][r] + bv;
                if (OUT_BF16)
                    ((unsigned short*)Cout)[(size_t)row * N + col] = f2bf(v);
                else
                    ((float*)Cout)[(size_t)row * N + col] = v;
            }
        }
    }
}

// ---------------- bias precompute: TRANSPOSED dense [16][t=64][q=64] fp32 ---
// bias_T[h][t][q]; padded t rows carry the key mask (-1e30), padded q cols 0.
__global__ void bias_pre_kernel(const float* __restrict__ bias_table,
                                const int* __restrict__ rel_idx,
                                float* __restrict__ bias_T) {
    int h = blockIdx.x;
    for (int i = threadIdx.x; i < 64 * 64; i += 256) {
        int t = i >> 6, q = i & 63;
        float v;
        if (t >= NTOK) v = -1e30f;                  // mask padded key tokens
        else if (q >= NTOK) v = 0.f;                // padded query rows: don't care
        else v = bias_table[rel_idx[q * NTOK + t] * HEADS + h];
        bias_T[h * 4096 + i] = v;
    }
}

// ---------------- MFMA attention: one wave per (window, head) ---------------
// 32x32x16 MFMA, swapped QK^T (S^T = K·Q^T) so softmax reduces over the
// register dim; P rebuilt in-register (pack bf16 + one half-wave shuffle) and
// fed straight to PV as the A operand. Only V^T lives in LDS (8 KB/wave).
// XOR-swizzle: element (row, t) of V^T stored at row*64 + (t ^ ((row&7)<<3)).
#define SWZ(row, t) ((t) ^ (((row) & 7) << 3))

__global__ __launch_bounds__(256, 4)
void attn_mfma_kernel(const unsigned short* __restrict__ Q,
                      const unsigned short* __restrict__ K,
                      const unsigned short* __restrict__ V,
                      const float* __restrict__ bias_T,
                      unsigned short* __restrict__ ctx) {
    __shared__ unsigned short Vt[4][64 * 64];  // per-wave V^T slice [d][tok]

    const int tid = threadIdx.x;
    const int w = tid >> 6;
    const int lane = tid & 63;
    const int p = blockIdx.x * 4 + w;          // 4 heads of the same window per block
    const int b = p >> 4;
    const int h = p & 15;
    const size_t base = (size_t)(b * NTOK) * DIM + h * HEAD_DIM;
    unsigned short* vt = Vt[w];

    const int l31 = lane & 31;
    const int hi = lane >> 5;

    // ---- V global loads first (latency hidden under QK^T) ----
    // lane&15 = token group, lane>>4 = d quad -> transposed writes spread banks
    ushort4 vreg[16];
    const int vtok0 = lane & 15;
    const int vd0 = (lane >> 4) * 4;
#pragma unroll
    for (int tb = 0; tb < 4; ++tb) {
        const int tok = vtok0 + 16 * tb;
        const bool valid = tok < NTOK;
#pragma unroll
        for (int db = 0; db < 4; ++db) {
            const int d0 = vd0 + 16 * db;
            vreg[tb * 4 + db] = valid ? *(const ushort4*)&V[base + (size_t)tok * DIM + d0]
                                      : make_ushort4(0, 0, 0, 0);
        }
    }

    // ---- K fragments (A operand of S^T): K[t = tt*32+l31][d = dk*16+hi*8+j]
    bf16x8 af_k[2][4];
#pragma unroll
    for (int tt = 0; tt < 2; ++tt)
#pragma unroll
        for (int dk = 0; dk < 4; ++dk)
            af_k[tt][dk] = *(const bf16x8*)&K[base + (size_t)(tt * 32 + l31) * DIM + dk * 16 + hi * 8];

    // ---- V^T into LDS (swizzled): ~4-way max conflicts with this indexing
#pragma unroll
    for (int tb = 0; tb < 4; ++tb) {
        const int tok = vtok0 + 16 * tb;
#pragma unroll
        for (int db = 0; db < 4; ++db) {
            const int d0 = vd0 + 16 * db;
            ushort4 vv = vreg[tb * 4 + db];
            vt[(d0 + 0) * 64 + SWZ(d0 + 0, tok)] = vv.x;
            vt[(d0 + 1) * 64 + SWZ(d0 + 1, tok)] = vv.y;
            vt[(d0 + 2) * 64 + SWZ(d0 + 2, tok)] = vv.z;
            vt[(d0 + 3) * 64 + SWZ(d0 + 3, tok)] = vv.w;
        }
    }

    const float* bT = bias_T + h * 4096;
    uintx4 pa[2][4];  // P as PV A-frags: [tq][kt] -> 4 dwords = 8 bf16

#pragma unroll
    for (int tq = 0; tq < 2; ++tq) {
        // Q fragments (B operand): Q[q = tq*32+l31][d-slice]
        bf16x8 bf_q[4];
#pragma unroll
        for (int dk = 0; dk < 4; ++dk)
            bf_q[dk] = *(const bf16x8*)&Q[base + (size_t)(tq * 32 + l31) * DIM + dk * 16 + hi * 8];

        // S^T tiles: s[tt][r] = S^T[t = tt*32 + crow(r,hi)][q = tq*32 + l31]
        floatx16 s[2] = {};
#pragma unroll
        for (int dk = 0; dk < 4; ++dk)
#pragma unroll
            for (int tt = 0; tt < 2; ++tt)
                s[tt] = __builtin_amdgcn_mfma_f32_32x32x16_bf16(
                    af_k[tt][dk], bf_q[dk], s[tt], 0, 0, 0);

        // scale + bias (bias_T[t][q]: q = lanes -> coalesced)
        float x[32];
#pragma unroll
        for (int tt = 0; tt < 2; ++tt)
#pragma unroll
            for (int r = 0; r < 16; ++r) {
                const int t = tt * 32 + (r & 3) + 8 * (r >> 2) + 4 * hi;
                x[tt * 16 + r] = s[tt][r] * SCALEF + bT[t * 64 + tq * 32 + l31];
            }

        // row max over t: in-register tree + one half-wave shuffle
        float m0[16];
#pragma unroll
        for (int i = 0; i < 16; ++i) m0[i] = fmaxf(x[i], x[i + 16]);
#pragma unroll
        for (int i = 0; i < 8; ++i) m0[i] = fmaxf(m0[i], m0[i + 8]);
#pragma unroll
        for (int i = 0; i < 4; ++i) m0[i] = fmaxf(m0[i], m0[i + 4]);
        float m = fmaxf(fmaxf(m0[0], m0[1]), fmaxf(m0[2], m0[3]));
        m = fmaxf(m, __shfl_xor(m, 32));

#pragma unroll
        for (int i = 0; i < 32; ++i) x[i] = __expf(x[i] - m);

        float t0s[16];
#pragma unroll
        for (int i = 0; i < 16; ++i) t0s[i] = x[i] + x[i + 16];
#pragma unroll
        for (int i = 0; i < 8; ++i) t0s[i] += t0s[i + 8];
#pragma unroll
        for (int i = 0; i < 4; ++i) t0s[i] += t0s[i + 4];
        float sum = (t0s[0] + t0s[1]) + (t0s[2] + t0s[3]);
        sum += __shfl_xor(sum, 32);
        const float inv = 1.f / sum;

        // Build P A-frags in-register: P[q = tq*32+l31][t = kt*16 + hi*8 + j].
        // Source reg for elem j: r = 8*(kt&1) + 4*hi_dest + (j&3) in tile kt>>1,
        // from half hi' = (j>=4). Each lane packs its 8 regs, one shfl_xor(32)
        // exchanges halves, cndmask selects.
#pragma unroll
        for (int kt = 0; kt < 4; ++kt) {
            const int B0 = (kt >> 1) * 16 + (kt & 1) * 8;
            unsigned int a0 = ((unsigned int)f2bf(x[B0 + 1] * inv) << 16) | f2bf(x[B0 + 0] * inv);
            unsigned int a1 = ((unsigned int)f2bf(x[B0 + 3] * inv) << 16) | f2bf(x[B0 + 2] * inv);
            unsigned int a2 = ((unsigned int)f2bf(x[B0 + 5] * inv) << 16) | f2bf(x[B0 + 4] * inv);
            unsigned int a3 = ((unsigned int)f2bf(x[B0 + 7] * inv) << 16) | f2bf(x[B0 + 6] * inv);
            unsigned int s0 = __shfl_xor(a0, 32);
            unsigned int s1 = __shfl_xor(a1, 32);
            unsigned int s2 = __shfl_xor(a2, 32);
            unsigned int s3 = __shfl_xor(a3, 32);
            uintx4 wv;
            wv[0] = hi ? s2 : a0;
            wv[1] = hi ? s3 : a1;
            wv[2] = hi ? a2 : s0;
            wv[3] = hi ? a3 : s1;
            pa[tq][kt] = wv;
        }
    }

    // ---- PV: O[q][d] = sum_t P[q][t] V^T[d][t] ----
    floatx16 o[2][2] = {};
#pragma unroll
    for (int kt = 0; kt < 4; ++kt) {
        const int t0 = kt * 16 + hi * 8;
        bf16x8 bv[2];
#pragma unroll
        for (int td = 0; td < 2; ++td) {
            const int row = td * 32 + l31;
            bv[td] = *(const bf16x8*)&vt[row * 64 + SWZ(row, t0)];
        }
#pragma unroll
        for (int tq = 0; tq < 2; ++tq) {
            const bf16x8 ap = __builtin_bit_cast(bf16x8, pa[tq][kt]);
#pragma unroll
            for (int td = 0; td < 2; ++td)
                o[tq][td] = __builtin_amdgcn_mfma_f32_32x32x16_bf16(
                    ap, bv[td], o[tq][td], 0, 0, 0);
        }
    }

    // ---- store ctx (bf16): O[q = tq*32 + crow(r,hi)][d = td*32 + l31] ----
#pragma unroll
    for (int tq = 0; tq < 2; ++tq)
#pragma unroll
        for (int r = 0; r < 16; ++r) {
            const int q = tq * 32 + (r & 3) + 8 * (r >> 2) + 4 * hi;
            if (q < NTOK) {
#pragma unroll
                for (int td = 0; td < 2; ++td)
                    ctx[base + (size_t)q * DIM + td * 32 + l31] = f2bf(o[tq][td][r]);
            }
        }
}

// ---------------- launch ----------------------------------------------------
extern "C" void kernel_launch(void* const* d_in, const int* in_sizes, int n_in,
                              void* d_out, int out_size, void* d_ws, size_t ws_size,
                              hipStream_t stream) {
    const float* landmark = (const float*)d_in[0];
    const float* image    = (const float*)d_in[1];
    const float* Wq = (const float*)d_in[2];
    const float* bq = (const float*)d_in[3];
    const float* Wk = (const float*)d_in[4];
    const float* bk = (const float*)d_in[5];
    const float* Wv = (const float*)d_in[6];
    const float* bv = (const float*)d_in[7];
    const float* Wo = (const float*)d_in[8];
    const float* bo = (const float*)d_in[9];
    const float* bias_table = (const float*)d_in[10];
    const int*   rel_idx    = (const int*)d_in[11];
    float* out = (float*)d_out;

    const size_t FEAT = (size_t)1024 * NTOK * DIM;
    const size_t FB   = FEAT * 2;
    const size_t WB   = (size_t)DIM * DIM * 2;
    char* ws = (char*)d_ws;
    unsigned short* Qb  = (unsigned short*)(ws + 0 * FB);
    unsigned short* Kb  = (unsigned short*)(ws + 1 * FB);
    unsigned short* Vb  = (unsigned short*)(ws + 2 * FB);
    unsigned short* Lb  = (unsigned short*)(ws + 3 * FB);
    unsigned short* Ctx = (unsigned short*)(ws + 3 * FB); // aliases Lb (dead after Q GEMM)
    unsigned short* Ib  = (unsigned short*)(ws + 4 * FB);
    float* bias_dense   = (float*)(ws + 4 * FB);          // aliases Ib (dead after V GEMM)
    unsigned short* Wqb = (unsigned short*)(ws + 5 * FB + 0 * WB);
    unsigned short* Wkb = (unsigned short*)(ws + 5 * FB + 1 * WB);
    unsigned short* Wvb = (unsigned short*)(ws + 5 * FB + 2 * WB);
    unsigned short* Wob = (unsigned short*)(ws + 5 * FB + 3 * WB);

    cvt2_kernel<<<(int)(FEAT / 4 / 256), 256, 0, stream>>>(landmark, image, Lb, Ib, (int)FEAT);
    cvt2_kernel<<<(int)(DIM * DIM / 4 / 256), 256, 0, stream>>>(Wq, Wk, Wqb, Wkb, DIM * DIM);
    cvt2_kernel<<<(int)(DIM * DIM / 4 / 256), 256, 0, stream>>>(Wv, Wo, Wvb, Wob, DIM * DIM);

    dim3 ggrid(1024 / 128, 50176 / 128);
    gemm_bt_kernel<true><<<ggrid, 256, 0, stream>>>(Lb, Wqb, bq, Qb);
    gemm_bt_kernel<true><<<ggrid, 256, 0, stream>>>(Ib, Wkb, bk, Kb);
    gemm_bt_kernel<true><<<ggrid, 256, 0, stream>>>(Ib, Wvb, bv, Vb);

    bias_pre_kernel<<<HEADS, 256, 0, stream>>>(bias_table, rel_idx, bias_dense);

    attn_mfma_kernel<<<1024 * HEADS / 4, 256, 0, stream>>>(Qb, Kb, Vb, bias_dense, Ctx);

    gemm_bt_kernel<false><<<ggrid, 256, 0, stream>>>(Ctx, Wob, bo, out);
}